// Round 7
// baseline (231.205 us; speedup 1.0000x reference)
//
#include <hip/hip_runtime.h>

// Fokker-Planck 2D explicit update on MI355X (gfx950), round 4:
// - block = 256 threads = 4 waves = 4 consecutive x-rows (one full row per wave)
// - 8 outputs per thread along y (2x float4), all loads aligned float4
// - y-window edge products via intra-wave __shfl
// - __launch_bounds__(256,2): allow ~256 VGPR so ALL loads stay in flight
//   (round-3 compiler chose 80 VGPR -> load batching -> serialized latency)
// - interior waves skip u3-row loads (weight v3 == 0 there)
// f' = max(f + dt * (-div(A f) + 0.5 * div^2(B f)), 0)

constexpr int NXc = 512;
constexpr int NYc = 512;
constexpr int NBc = 32;

struct F8 { float4 lo, hi; };

__device__ __forceinline__ float4 mul4(float4 p, float4 q) {
    float4 r; r.x = p.x*q.x; r.y = p.y*q.y; r.z = p.z*q.z; r.w = p.w*q.w; return r;
}
__device__ __forceinline__ float4 fma4s(float s, float4 p, float4 acc) {
    acc.x = fmaf(s, p.x, acc.x); acc.y = fmaf(s, p.y, acc.y);
    acc.z = fmaf(s, p.z, acc.z); acc.w = fmaf(s, p.w, acc.w); return acc;
}
__device__ __forceinline__ F8 mul8(const F8& a, const F8& b) {
    F8 r; r.lo = mul4(a.lo, b.lo); r.hi = mul4(a.hi, b.hi); return r;
}
__device__ __forceinline__ F8 fma8s(float s, const F8& p, const F8& acc) {
    F8 r; r.lo = fma4s(s, p.lo, acc.lo); r.hi = fma4s(s, p.hi, acc.hi); return r;
}
__device__ __forceinline__ F8 add8(const F8& a, const F8& b) {
    F8 r;
    r.lo.x = a.lo.x+b.lo.x; r.lo.y = a.lo.y+b.lo.y; r.lo.z = a.lo.z+b.lo.z; r.lo.w = a.lo.w+b.lo.w;
    r.hi.x = a.hi.x+b.hi.x; r.hi.y = a.hi.y+b.hi.y; r.hi.z = a.hi.z+b.hi.z; r.hi.w = a.hi.w+b.hi.w;
    return r;
}

__device__ __forceinline__ F8 ld8(const float* __restrict__ p, int row, int y8) {
    const float* q = p + (size_t)row * NYc + y8;
    F8 r;
    r.lo = *reinterpret_cast<const float4*>(q);
    r.hi = *reinterpret_cast<const float4*>(q + 4);
    return r;
}

// product window: 8 per-lane products + neighbors via wave shuffle
struct W8 { float4 lo, hi; float m1, p8; };

__device__ __forceinline__ W8 mkwin8(const F8& a, const F8& f) {
    W8 w;
    w.lo = mul4(a.lo, f.lo);
    w.hi = mul4(a.hi, f.hi);
    w.m1 = __shfl_up(w.hi.w, 1);    // lane L-1's y8+7 == our y8-1 (garbage at lane 0, unused)
    w.p8 = __shfl_down(w.lo.x, 1);  // lane L+1's y8+0 == our y8+8 (garbage at lane 63, unused)
    return w;
}

// first derivative along y for the 8 outputs of this lane
__device__ __forceinline__ F8 dy8(const W8& w, bool atY0, bool atYN) {
    F8 r;
    r.lo.x = atY0 ? (-1.5f*w.lo.x + 2.0f*w.lo.y - 0.5f*w.lo.z) : 0.5f*(w.lo.y - w.m1);
    r.lo.y = 0.5f*(w.lo.z - w.lo.x);
    r.lo.z = 0.5f*(w.lo.w - w.lo.y);
    r.lo.w = 0.5f*(w.hi.x - w.lo.z);
    r.hi.x = 0.5f*(w.hi.y - w.lo.w);
    r.hi.y = 0.5f*(w.hi.z - w.hi.x);
    r.hi.z = 0.5f*(w.hi.w - w.hi.y);
    r.hi.w = atYN ? (1.5f*w.hi.w - 2.0f*w.hi.z + 0.5f*w.hi.y) : 0.5f*(w.p8 - w.hi.z);
    return r;
}
// second derivative along y
__device__ __forceinline__ F8 dyy8(const W8& w, bool atY0, bool atYN) {
    F8 r;
    r.lo.x = atY0 ? (2.0f*w.lo.x - 5.0f*w.lo.y + 4.0f*w.lo.z - w.lo.w)
                  : (w.lo.y - 2.0f*w.lo.x + w.m1);
    r.lo.y = w.lo.z - 2.0f*w.lo.y + w.lo.x;
    r.lo.z = w.lo.w - 2.0f*w.lo.z + w.lo.y;
    r.lo.w = w.hi.x - 2.0f*w.lo.w + w.lo.z;
    r.hi.x = w.hi.y - 2.0f*w.hi.x + w.lo.w;
    r.hi.y = w.hi.z - 2.0f*w.hi.y + w.hi.x;
    r.hi.z = w.hi.w - 2.0f*w.hi.z + w.hi.y;
    r.hi.w = atYN ? (2.0f*w.hi.w - 5.0f*w.hi.z + 4.0f*w.hi.y - w.hi.x)
                  : (w.p8 - 2.0f*w.hi.w + w.hi.z);
    return r;
}

__global__ __launch_bounds__(256, 2) void fp2d_kernel(
    const float* __restrict__ f,
    const float* __restrict__ dt,
    const float* __restrict__ A,
    const float* __restrict__ Bm,
    float* __restrict__ out)
{
    const int tid  = threadIdx.x;
    const int wv   = tid >> 6;            // wave id 0..3 -> row offset
    const int lane = tid & 63;
    const int b    = blockIdx.x >> 7;     // 128 blocks per batch plane
    const int x    = ((blockIdx.x & 127) << 2) + wv;   // wave-uniform
    const int y8   = lane << 3;           // 0..504

    const bool atY0 = (lane == 0);
    const bool atYN = (lane == 63);

    const size_t plane = (size_t)NXc * NYc;
    const float* fb = f  + (size_t)b * plane;
    const float* A0 = A  + (size_t)b * 2 * plane;
    const float* A1 = A0 + plane;
    const float* B0 = Bm + (size_t)b * 3 * plane;
    const float* B1 = B0 + plane;
    const float* B2 = B1 + plane;

    // ----- x-direction stencils (wave-uniform selection) -----
    int xa, xb_, xc, u3; float wxa, wxb, wxc, v0, v1, v2, v3;
    if (x == 0) {
        xa = 0; xb_ = 1; xc = 2; u3 = 3;
        wxa = -1.5f; wxb = 2.0f; wxc = -0.5f;
        v0 = 2.0f; v1 = -5.0f; v2 = 4.0f; v3 = -1.0f;
    } else if (x == NXc - 1) {
        xa = NXc - 1; xb_ = NXc - 2; xc = NXc - 3; u3 = NXc - 4;
        wxa = 1.5f; wxb = -2.0f; wxc = 0.5f;
        v0 = 2.0f; v1 = -5.0f; v2 = 4.0f; v3 = -1.0f;
    } else {
        xa = x - 1; xb_ = x; xc = x + 1; u3 = x;
        wxa = -0.5f; wxb = 0.0f; wxc = 0.5f;
        v0 = 1.0f; v1 = -2.0f; v2 = 1.0f; v3 = 0.0f;
    }
    const bool xInt = (x > 0) && (x < NXc - 1);

    // ----- loads: 14 rows x 2 float4 (u3 rows only at boundary waves) -----
    F8 f_a = ld8(fb, xa, y8);
    F8 f_b = ld8(fb, xb_, y8);
    F8 f_c = ld8(fb, xc, y8);

    F8 a0a = ld8(A0, xa, y8), a0b = ld8(A0, xb_, y8), a0c = ld8(A0, xc, y8);
    F8 a1x = ld8(A1, x, y8);
    F8 b0a = ld8(B0, xa, y8), b0b = ld8(B0, xb_, y8), b0c = ld8(B0, xc, y8);
    F8 b1x = ld8(B1, x, y8);
    F8 b2a = ld8(B2, xa, y8), b2b = ld8(B2, xb_, y8), b2c = ld8(B2, xc, y8);

    // u3 row: interior weight v3 == 0, so only boundary waves need real data
    F8 f_u, b0u;
    if (xInt) { f_u = f_b; b0u = b0b; }            // value multiplied by 0
    else      { f_u = ld8(fb, u3, y8); b0u = ld8(B0, u3, y8); }

    // center row for Dy/Dyy/output: interior -> xb_, boundary -> xa (uniform select)
    F8 fX;
    fX.lo = xInt ? f_b.lo : f_a.lo;
    fX.hi = xInt ? f_b.hi : f_a.hi;

    F8 zero8; zero8.lo = make_float4(0.f,0.f,0.f,0.f); zero8.hi = zero8.lo;

    // ----- gradv = Dx(A0 f) + Dy(A1 f) -----
    F8 gradv = fma8s(wxa, mul8(a0a, f_a),
               fma8s(wxb, mul8(a0b, f_b),
               fma8s(wxc, mul8(a0c, f_c), zero8)));
    W8 wA1 = mkwin8(a1x, fX);
    gradv = add8(gradv, dy8(wA1, atY0, atYN));

    // ----- dxx = Dxx(B0 f) -----
    F8 dxx = fma8s(v0, mul8(b0a, f_a),
             fma8s(v1, mul8(b0b, f_b),
             fma8s(v2, mul8(b0c, f_c),
             fma8s(v3, mul8(b0u, f_u), zero8))));

    // ----- dyy = Dyy(B1 f) -----
    W8 wB1 = mkwin8(b1x, fX);
    F8 dyy = dyy8(wB1, atY0, atYN);

    // ----- cross = DxDy(B2 f)  (doubled later via 0.5*2) -----
    W8 wB2a = mkwin8(b2a, f_a);
    W8 wB2b = mkwin8(b2b, f_b);
    W8 wB2c = mkwin8(b2c, f_c);
    F8 cross = fma8s(wxa, dy8(wB2a, atY0, atYN),
               fma8s(wxb, dy8(wB2b, atY0, atYN),
               fma8s(wxc, dy8(wB2c, atY0, atYN), zero8)));

    // ----- combine: df = 0.5*(dxx+dyy) + cross - gradv; out = max(f + dt*df, 0) -----
    const float dtb = dt[b];
    float* orow = out + (size_t)b * plane + (size_t)x * NYc + y8;

    float4 r0, r1;
    r0.x = fmaxf(fmaf(0.5f*(dxx.lo.x + dyy.lo.x) + cross.lo.x - gradv.lo.x, dtb, fX.lo.x), 0.0f);
    r0.y = fmaxf(fmaf(0.5f*(dxx.lo.y + dyy.lo.y) + cross.lo.y - gradv.lo.y, dtb, fX.lo.y), 0.0f);
    r0.z = fmaxf(fmaf(0.5f*(dxx.lo.z + dyy.lo.z) + cross.lo.z - gradv.lo.z, dtb, fX.lo.z), 0.0f);
    r0.w = fmaxf(fmaf(0.5f*(dxx.lo.w + dyy.lo.w) + cross.lo.w - gradv.lo.w, dtb, fX.lo.w), 0.0f);
    r1.x = fmaxf(fmaf(0.5f*(dxx.hi.x + dyy.hi.x) + cross.hi.x - gradv.hi.x, dtb, fX.hi.x), 0.0f);
    r1.y = fmaxf(fmaf(0.5f*(dxx.hi.y + dyy.hi.y) + cross.hi.y - gradv.hi.y, dtb, fX.hi.y), 0.0f);
    r1.z = fmaxf(fmaf(0.5f*(dxx.hi.z + dyy.hi.z) + cross.hi.z - gradv.hi.z, dtb, fX.hi.z), 0.0f);
    r1.w = fmaxf(fmaf(0.5f*(dxx.hi.w + dyy.hi.w) + cross.hi.w - gradv.hi.w, dtb, fX.hi.w), 0.0f);

    *reinterpret_cast<float4*>(orow)     = r0;
    *reinterpret_cast<float4*>(orow + 4) = r1;
}

extern "C" void kernel_launch(void* const* d_in, const int* in_sizes, int n_in,
                              void* d_out, int out_size, void* d_ws, size_t ws_size,
                              hipStream_t stream) {
    const float* f  = (const float*)d_in[0];
    const float* dt = (const float*)d_in[1];
    const float* A  = (const float*)d_in[2];
    const float* Bm = (const float*)d_in[3];
    float* out = (float*)d_out;

    const int blocks = NBc * NXc / 4;   // 4096 blocks: 4 rows per block
    fp2d_kernel<<<blocks, 256, 0, stream>>>(f, dt, A, Bm, out);
}